// Round 2
// baseline (148.919 us; speedup 1.0000x reference)
//
#include <hip/hip_runtime.h>

// Single fused kernel, value-partitioned by 2048-site bins (4096 bins, 2x
// device capacity for inter-block pipelining). Both slice_sites (ss) and
// addr2site_map (a2s) are sorted, so block g owns site range
// [g*2048,(g+1)*2048) on BOTH sides:
//   1. 4 wave-parallel binary searches find e0,e1 (a2s range) and f0,f1
//      (ss range).
//   2. mark loads issue first, probe (ss/sc) loads issue right behind them
//      into registers -- vmcnt is in-order, so mark compute waits only on
//      its own loads while probe data streams in underneath.
//   3. mark: 64-word LDS bitmap from a2s[e0..e1) where sig>0
//      (register-merged LDS atomics).
//   4. probe: prefetched registers tested against the LDS bitmap, outputs
//      streamed NT to the block's contiguous slice (store-only phase).

typedef int   v4i __attribute__((ext_vector_type(4)));
typedef float v4f __attribute__((ext_vector_type(4)));

static constexpr int BIN_SHIFT     = 11;
static constexpr int SITES_PER_BIN = 1 << BIN_SHIFT;        // 2048
static constexpr int WORDS_PER_BIN = SITES_PER_BIN / 32;    // 64
static constexpr int NBINS         = 1 << (23 - BIN_SHIFT); // 4096 (2^23 sites)
static constexpr int BLOCK         = 256;
static constexpr int PF            = 2;   // prefetched vec4 pairs / thread

__device__ __forceinline__ int lower_bound_dev(
    const int* __restrict__ a, int n, int key)
{
    int lo = 0, hi = n;
    while (lo < hi) {
        const int mid = (lo + hi) >> 1;
        if (a[mid] < key) lo = mid + 1; else hi = mid;
    }
    return lo;
}

__global__ __launch_bounds__(BLOCK, 8) void fused_kernel(
    const int* __restrict__ ss, const int* __restrict__ sig,
    const int* __restrict__ a2s, const float* __restrict__ sc,
    float* __restrict__ rem, float* __restrict__ avail,
    int n_clb, int n_slice)
{
    __shared__ unsigned int lbm[WORDS_PER_BIN];
    __shared__ int sb[4];

    const int g        = blockIdx.x;
    const int siteBase = g << BIN_SHIFT;
    const int siteEnd  = siteBase + SITES_PER_BIN;

    if (threadIdx.x < WORDS_PER_BIN) lbm[threadIdx.x] = 0u;

    // --- boundaries: one binary search per wave (chains overlap) -----------
    if ((threadIdx.x & 63) == 0) {
        const int w = threadIdx.x >> 6;
        int r;
        if      (w == 0) r = lower_bound_dev(a2s, n_clb,   siteBase);
        else if (w == 1) r = lower_bound_dev(a2s, n_clb,   siteEnd);
        else if (w == 2) r = lower_bound_dev(ss,  n_slice, siteBase);
        else             r = lower_bound_dev(ss,  n_slice, siteEnd);
        sb[w] = r;
    }
    __syncthreads();
    const int e0 = sb[0], e1 = sb[1], f0 = sb[2], f1 = sb[3];

    // --- mark chunk 1: ISSUE loads (consumed below) -------------------------
    // 8 entries/thread covers 2048 entries/block; typical bin has ~1465, so
    // one chunk nearly always suffices; loop below handles any excess.
    const int mstart = e0 & ~3;
    const int s0 = mstart + (int)threadIdx.x * 8;
    const bool have1 = s0 < e1;
    int av[8], gv[8];
    if (have1) {
        if (s0 + 8 <= n_clb) {
            v4i a0 = __builtin_nontemporal_load((const v4i*)(a2s + s0));
            v4i a1 = __builtin_nontemporal_load((const v4i*)(a2s + s0 + 4));
            v4i g0 = __builtin_nontemporal_load((const v4i*)(sig + s0));
            v4i g1 = __builtin_nontemporal_load((const v4i*)(sig + s0 + 4));
            av[0]=a0.x; av[1]=a0.y; av[2]=a0.z; av[3]=a0.w;
            av[4]=a1.x; av[5]=a1.y; av[6]=a1.z; av[7]=a1.w;
            gv[0]=g0.x; gv[1]=g0.y; gv[2]=g0.z; gv[3]=g0.w;
            gv[4]=g1.x; gv[5]=g1.y; gv[6]=g1.z; gv[7]=g1.w;
        } else {
#pragma unroll
            for (int j = 0; j < 8; ++j) {
                const int i = s0 + j;
                const bool ok = i < n_clb;
                av[j] = ok ? a2s[i] : -1;
                gv[j] = ok ? sig[i] : 0;
            }
        }
    }

    // --- probe prefetch: ISSUE loads (consumed after the mark barrier) ------
    const int fa = (f0 + 3) & ~3;          // first vec4-aligned index
    const int fb = f1 & ~3;                // end of vec4 region
    const int q0 = fa >> 2;
    const int qn = fb >> 2;
    v4i ps[PF]; v4f pfv[PF];
#pragma unroll
    for (int k = 0; k < PF; ++k) {
        const int q = q0 + (int)threadIdx.x + k * BLOCK;
        if (q < qn) {
            ps[k]  = __builtin_nontemporal_load((const v4i*)ss + q);
            pfv[k] = __builtin_nontemporal_load((const v4f*)sc + q);
        }
    }

    // --- mark compute chunk 1 (register-merged LDS atomics) -----------------
    if (have1) {
        unsigned int curw = 0xFFFFFFFFu, curm = 0u;
#pragma unroll
        for (int j = 0; j < 8; ++j) {
            const int site = av[j];
            if (gv[j] > 0 && site >= siteBase && site < siteEnd) {
                const unsigned int u = (unsigned int)(site - siteBase);
                const unsigned int w = u >> 5;
                const unsigned int m = 1u << (u & 31u);
                if (w == curw) curm |= m;
                else { if (curm) atomicOr(&lbm[curw], curm); curw = w; curm = m; }
            }
        }
        if (curm) atomicOr(&lbm[curw], curm);
    }
    // rare extra chunks (bin with > 2048 a2s entries)
    for (int s = s0 + BLOCK * 8; s < e1; s += BLOCK * 8) {
        int xv[8], yv[8];
#pragma unroll
        for (int j = 0; j < 8; ++j) {
            const int i = s + j;
            const bool ok = i < n_clb;
            xv[j] = ok ? a2s[i] : -1;
            yv[j] = ok ? sig[i] : 0;
        }
        unsigned int curw = 0xFFFFFFFFu, curm = 0u;
#pragma unroll
        for (int j = 0; j < 8; ++j) {
            const int site = xv[j];
            if (yv[j] > 0 && site >= siteBase && site < siteEnd) {
                const unsigned int u = (unsigned int)(site - siteBase);
                const unsigned int w = u >> 5;
                const unsigned int m = 1u << (u & 31u);
                if (w == curw) curm |= m;
                else { if (curm) atomicOr(&lbm[curw], curm); curw = w; curm = m; }
            }
        }
        if (curm) atomicOr(&lbm[curw], curm);
    }

    __syncthreads();

    // --- probe: registers vs LDS bitmap, contiguous output slice ------------
    const int head_end = fa < f1 ? fa : f1;

    // scalar head (<=3 elements)
    {
        const int i = f0 + (int)threadIdx.x;
        if (i < head_end) {
            const unsigned int u   = (unsigned int)(ss[i] - siteBase);
            const unsigned int bit = (lbm[u >> 5] >> (u & 31u)) & 1u;
            rem[i]   = bit ? 0.0f : 1.0f;
            avail[i] = bit ? 0.0f : sc[i];
        }
    }
    // prefetched vec4 body (store-only: data already in registers)
#pragma unroll
    for (int k = 0; k < PF; ++k) {
        const int q = q0 + (int)threadIdx.x + k * BLOCK;
        if (q < qn) {
            v4f r, a;
#pragma unroll
            for (int j = 0; j < 4; ++j) {
                const unsigned int u   = (unsigned int)(ps[k][j] - siteBase);
                const unsigned int bit = (lbm[u >> 5] >> (u & 31u)) & 1u;
                r[j] = bit ? 0.0f : 1.0f;
                a[j] = bit ? 0.0f : pfv[k][j];
            }
            __builtin_nontemporal_store(r, (v4f*)rem + q);
            __builtin_nontemporal_store(a, (v4f*)avail + q);
        }
    }
    // rare fallback (bin with > 2048 slice sites)
    for (int q = q0 + PF * BLOCK + (int)threadIdx.x; q < qn; q += BLOCK) {
        v4i s = __builtin_nontemporal_load((const v4i*)ss + q);
        v4f f = __builtin_nontemporal_load((const v4f*)sc + q);
        v4f r, a;
#pragma unroll
        for (int j = 0; j < 4; ++j) {
            const unsigned int u   = (unsigned int)(s[j] - siteBase);
            const unsigned int bit = (lbm[u >> 5] >> (u & 31u)) & 1u;
            r[j] = bit ? 0.0f : 1.0f;
            a[j] = bit ? 0.0f : f[j];
        }
        __builtin_nontemporal_store(r, (v4f*)rem + q);
        __builtin_nontemporal_store(a, (v4f*)avail + q);
    }
    // scalar tail (<=3 elements)
    {
        const int tstart = fb > head_end ? fb : head_end;
        const int i = tstart + (int)threadIdx.x;
        if (i < f1) {
            const unsigned int u   = (unsigned int)(ss[i] - siteBase);
            const unsigned int bit = (lbm[u >> 5] >> (u & 31u)) & 1u;
            rem[i]   = bit ? 0.0f : 1.0f;
            avail[i] = bit ? 0.0f : sc[i];
        }
    }
}

extern "C" void kernel_launch(void* const* d_in, const int* in_sizes, int n_in,
                              void* d_out, int out_size, void* d_ws, size_t ws_size,
                              hipStream_t stream) {
    const int*   ss  = (const int*)d_in[0];
    const int*   sig = (const int*)d_in[1];
    const int*   a2s = (const int*)d_in[2];
    const float* sc  = (const float*)d_in[3];
    const int n_slice = in_sizes[0];
    const int n_clb   = in_sizes[1];

    float* rem   = (float*)d_out;
    float* avail = rem + n_slice;

    fused_kernel<<<NBINS, BLOCK, 0, stream>>>(ss, sig, a2s, sc, rem, avail,
                                              n_clb, n_slice);
}

// Round 3
// 147.786 us; speedup vs baseline: 1.0077x; 1.0077x over previous
//
#include <hip/hip_runtime.h>

// Index-partitioned two-kernel pipeline over a 1 MiB global bitmap
// (site ids in [0, 2^23)). No boundary searches anywhere.
//  memset: zero the bitmap (hipMemsetAsync, ~1 us).
//  mark:   each thread streams 16 consecutive a2s/sig entries (8 NT vec4
//          loads in flight, fully coalesced), register-merges bits of
//          consecutive entries (avg ~23 entries/word), and emits ~1.7
//          merged global atomicOr per thread (~640K total -- L2 trivia).
//  probe:  one thread per vec4 of sorted ss/sc; bitmap reads are L2-hits
//          (each wave touches a ~700 B window of the 1 MiB bitmap);
//          NT streams out. Tail (<4 elems) folded into the same kernel.

typedef int   v4i __attribute__((ext_vector_type(4)));
typedef float v4f __attribute__((ext_vector_type(4)));

static constexpr int BLOCK  = 256;
static constexpr int MPT    = 16;                  // mark entries per thread
static constexpr int NSITES = 1 << 23;             // 2048 * 4096
static constexpr int NWORDS = NSITES / 32;         // 262144 words = 1 MiB

// ---- mark: streaming a2s/sig -> global bitmap via merged atomics ----------
__global__ __launch_bounds__(BLOCK) void mark_kernel(
    const int* __restrict__ sig, const int* __restrict__ a2s,
    unsigned int* __restrict__ bm, int n_clb)
{
    const int s = (blockIdx.x * BLOCK + threadIdx.x) * MPT;
    if (s >= n_clb) return;

    int av[MPT], gv[MPT];
    if (s + MPT <= n_clb) {
#pragma unroll
        for (int k = 0; k < MPT / 4; ++k) {
            v4i a = __builtin_nontemporal_load((const v4i*)(a2s + s + 4 * k));
            v4i g = __builtin_nontemporal_load((const v4i*)(sig + s + 4 * k));
            av[4*k+0] = a.x; av[4*k+1] = a.y; av[4*k+2] = a.z; av[4*k+3] = a.w;
            gv[4*k+0] = g.x; gv[4*k+1] = g.y; gv[4*k+2] = g.z; gv[4*k+3] = g.w;
        }
    } else {
#pragma unroll
        for (int j = 0; j < MPT; ++j) {
            const int i = s + j;
            const bool ok = i < n_clb;
            av[j] = ok ? a2s[i] : -1;
            gv[j] = ok ? sig[i] : 0;
        }
    }

    // register-merge consecutive entries into per-word masks
    unsigned int curw = 0xFFFFFFFFu, curm = 0u;
#pragma unroll
    for (int j = 0; j < MPT; ++j) {
        if (gv[j] > 0) {
            const unsigned int u = (unsigned int)av[j];
            const unsigned int w = u >> 5;
            const unsigned int m = 1u << (u & 31u);
            if (w == curw) curm |= m;
            else { if (curm) atomicOr(&bm[curw], curm); curw = w; curm = m; }
        }
    }
    if (curm) atomicOr(&bm[curw], curm);
}

// ---- probe: index-partitioned, bitmap L2-resident, NT stream out ----------
__global__ __launch_bounds__(BLOCK) void probe_kernel(
    const int* __restrict__ ss, const float* __restrict__ sc,
    const unsigned int* __restrict__ bm,
    float* __restrict__ rem, float* __restrict__ avail,
    int n4, int n_slice)
{
    const int q = blockIdx.x * BLOCK + threadIdx.x;
    if (q < n4) {
        v4i s = __builtin_nontemporal_load((const v4i*)ss + q);
        v4f f = __builtin_nontemporal_load((const v4f*)sc + q);
        v4f r, a;
#pragma unroll
        for (int j = 0; j < 4; ++j) {
            const unsigned int u   = (unsigned int)s[j];
            const unsigned int bit = (bm[u >> 5] >> (u & 31u)) & 1u;
            r[j] = bit ? 0.0f : 1.0f;
            a[j] = bit ? 0.0f : f[j];
        }
        __builtin_nontemporal_store(r, (v4f*)rem + q);
        __builtin_nontemporal_store(a, (v4f*)avail + q);
    } else if (q == n4) {
        // scalar tail (<= 3 elements), folded in to avoid a 4th launch
        for (int i = n4 * 4; i < n_slice; ++i) {
            const unsigned int u   = (unsigned int)ss[i];
            const unsigned int bit = (bm[u >> 5] >> (u & 31u)) & 1u;
            rem[i]   = bit ? 0.0f : 1.0f;
            avail[i] = bit ? 0.0f : sc[i];
        }
    }
}

extern "C" void kernel_launch(void* const* d_in, const int* in_sizes, int n_in,
                              void* d_out, int out_size, void* d_ws, size_t ws_size,
                              hipStream_t stream) {
    const int*   ss  = (const int*)d_in[0];
    const int*   sig = (const int*)d_in[1];
    const int*   a2s = (const int*)d_in[2];
    const float* sc  = (const float*)d_in[3];
    const int n_slice = in_sizes[0];
    const int n_clb   = in_sizes[1];

    unsigned int* bm = (unsigned int*)d_ws;  // 1 MiB bitmap

    hipMemsetAsync(bm, 0, NWORDS * sizeof(unsigned int), stream);

    const int mb = (n_clb + BLOCK * MPT - 1) / (BLOCK * MPT);
    mark_kernel<<<mb, BLOCK, 0, stream>>>(sig, a2s, bm, n_clb);

    float* rem   = (float*)d_out;
    float* avail = rem + n_slice;
    const int n4 = n_slice / 4;
    const int pb = (n4 + 1 + BLOCK - 1) / BLOCK;  // +1 thread for the tail
    probe_kernel<<<pb, BLOCK, 0, stream>>>(ss, sc, bm, rem, avail, n4, n_slice);
}